// Round 22
// baseline (151.708 us; speedup 1.0000x reference)
//
#include <hip/hip_runtime.h>
#include <hip/hip_bf16.h>

#define IN_F 256
#define OUT_F 128
#define BSH 7
#define BNODES 128          // nodes per bucket = 1<<BSH
#define MAXBUCK 1024        // supports n_nodes <= 131072
#define BIN1A_BLOCKS 256
#define BIN1B_BLOCKS 256
#define GEMM_BLOCKS 256
#define BM 32               // gemm rows per tile

typedef short bf16x8 __attribute__((ext_vector_type(8)));
typedef float f32x4 __attribute__((ext_vector_type(4)));
typedef unsigned short us8 __attribute__((ext_vector_type(8)));

__device__ __forceinline__ unsigned short f2bf(float x) {
    union { __hip_bfloat16 b; unsigned short u; } cv;
    cv.b = __float2bfloat16(x);
    return cv.u;
}
__device__ inline float bf2f(unsigned short x) {
    union { unsigned u; float f; } v; v.u = ((unsigned)x) << 16;
    return v.f;
}

// async 16B global -> LDS (DMA; wave-uniform LDS base + lane*16, per-lane gsrc)
__device__ __forceinline__ void gload_lds16(const void* g, void* l) {
    __builtin_amdgcn_global_load_lds(
        (const __attribute__((address_space(1))) unsigned int*)g,
        (__attribute__((address_space(3))) unsigned int*)l,
        16, 0, 0);
}

// ---------------------------------------------------------------------------
// K1 fused: blocks [0, BIN1A_BLOCKS) = bin1a (bucket histogram -> bhist AND
// per-block histogram row -> perbhist); blocks [BIN1A_BLOCKS,+128) = wprep.
// ---------------------------------------------------------------------------
__global__ __launch_bounds__(256) void prep_kernel(const float* __restrict__ W,
                                                   unsigned short* __restrict__ Wt,
                                                   const int* __restrict__ dst,
                                                   int* __restrict__ bhist,
                                                   int* __restrict__ perbhist,
                                                   int n_edges, int nbuck) {
    if ((int)blockIdx.x < BIN1A_BLOCKS) {
        __shared__ int hist[MAXBUCK];
        const int tid = threadIdx.x;
        const int chunk = (n_edges + BIN1A_BLOCKS - 1) / BIN1A_BLOCKS;
        const int lo = blockIdx.x * chunk;
        const int hi = min(lo + chunk, n_edges);

        for (int i = tid; i < MAXBUCK; i += 256) hist[i] = 0;
        __syncthreads();
        for (int e = lo + tid; e < hi; e += 256)
            atomicAdd(&hist[dst[e] >> BSH], 1);
        __syncthreads();
        int* myrow = perbhist + (size_t)blockIdx.x * MAXBUCK;
        for (int i = tid; i < nbuck; i += 256) {
            int c = hist[i];
            myrow[i] = c;
            if (c) atomicAdd(&bhist[i], c);
        }
    } else {
        int n = blockIdx.x - BIN1A_BLOCKS;   // 0..127
        int k = threadIdx.x;                 // 0..255
        Wt[n * IN_F + k] = f2bf(W[k * OUT_F + n]);
    }
}

// ---------------------------------------------------------------------------
// K2 fused (1024 thr, 64 KB shared union, __launch_bounds__(1024,8) pins
// VGPR<=64 so TWO blocks co-reside per CU = 128 KB LDS, 32 waves):
//   blocks [0, BIN1B_BLOCKS)  = bin1b (12 KB of the union)
//   blocks [BIN1B_BLOCKS, ..) = gemm  (As[2] = 64 KB, B in registers)
// The independent {bin chain} and {gemm} DAG branches now run CONCURRENTLY
// (one of each per CU); bin waves also cover gemm's per-tile drain stalls.
// Round-14's fusion failure is avoided by construction: union is 64 KB (not
// 96+), so co-residency arithmetic works: 2x64 KB <= 160 KB, 2x16 waves = 32.
// ---------------------------------------------------------------------------
__global__ __launch_bounds__(1024, 8) void gemm_bin_kernel(
        const float* __restrict__ feat, const unsigned short* __restrict__ Wt,
        unsigned short* __restrict__ h, int n_nodes,
        const int* __restrict__ src, const int* __restrict__ dst,
        const int* __restrict__ bhist, const int* __restrict__ perbhist,
        int* __restrict__ gcur0, unsigned* __restrict__ ebuf,
        int n_edges, int nbuck) {

    __shared__ __align__(16) char smem[65536];

    if ((int)blockIdx.x < BIN1B_BLOCKS) {
        // ---------------- bin1b (round-20 logic, smem union) ----------------
        int* scanv = (int*)smem;             // [MAXBUCK]
        int* hist  = scanv + MAXBUCK;        // [MAXBUCK]
        int* lbase = hist + MAXBUCK;         // [MAXBUCK]
        const int tid = threadIdx.x;
        const int chunk = (n_edges + BIN1B_BLOCKS - 1) / BIN1B_BLOCKS;
        const int lo = blockIdx.x * chunk;
        const int hi = min(lo + chunk, n_edges);

        int own = (tid < nbuck) ? bhist[tid] : 0;
        scanv[tid] = own;
        __syncthreads();
        #pragma unroll
        for (int off = 1; off < MAXBUCK; off <<= 1) {
            int t = (tid >= off) ? scanv[tid - off] : 0;
            __syncthreads();
            scanv[tid] += t;
            __syncthreads();
        }
        int bstart_t = scanv[tid] - own;   // exclusive
        __syncthreads();
        scanv[tid] = bstart_t;
        __syncthreads();

        if (tid < nbuck) {
            int c = perbhist[(size_t)blockIdx.x * MAXBUCK + tid];
            lbase[tid] = (c > 0) ? (scanv[tid] + atomicAdd(&gcur0[tid], c)) : 0;
            hist[tid] = 0;                 // local cursor
        }
        __syncthreads();
        for (int e = lo + tid; e < hi; e += 1024) {
            int d = dst[e];
            int bkt = d >> BSH;
            int off = atomicAdd(&hist[bkt], 1);
            ebuf[lbase[bkt] + off] = ((unsigned)src[e] << BSH) | (unsigned)(d & (BNODES - 1));
        }
    } else {
        // ---------------- gemm (2-deep async pipeline, B in regs) -----------
        float (*As)[BM * IN_F] = (float (*)[BM * IN_F])smem;   // As[2] = 64 KB

        const int tid  = threadIdx.x;
        const int wave = tid >> 6;          // 0..15
        const int lane = tid & 63;
        const int q    = lane >> 4;         // 0..3
        const int rr   = lane & 15;
        const int rowgrp = wave & 1;
        const int colgrp = wave >> 1;
        const int gb   = (int)blockIdx.x - BIN1B_BLOCKS;

        const int ntiles = (n_nodes + BM - 1) / BM;
        const int nit = (gb < ntiles)
                      ? ((ntiles - gb + GEMM_BLOCKS - 1) / GEMM_BLOCKS) : 0;

        const int brow = colgrp * 16 + rr;

        // B fragments -> registers, once (L2-hot Wt)
        bf16x8 bq[8];
        #pragma unroll
        for (int k0 = 0; k0 < 8; ++k0)
            bq[k0] = *reinterpret_cast<const bf16x8*>(
                Wt + (size_t)brow * IN_F + (k0 * 4 + q) * 8);

        // prologue: stage tile 0
        if (0 < nit) {
            const int R0 = gb * BM;
            #pragma unroll
            for (int ii = 0; ii < 2; ++ii) {
                int r  = ii * 16 + wave;
                int rg = R0 + r; if (rg >= n_nodes) rg = n_nodes - 1;
                gload_lds16(feat + (size_t)rg * IN_F + ((lane ^ (r & 7)) * 4),
                            &As[0][r * IN_F]);
            }
        }
        __syncthreads();

        const int arow = rowgrp * 16 + rr;

        int t = gb, buf = 0;
        for (int i = 0; i < nit; ++i, t += GEMM_BLOCKS) {
            // issue stage of tile i+1 into the other buffer
            if (i + 1 < nit) {
                const int R0n = (t + GEMM_BLOCKS) * BM;
                #pragma unroll
                for (int ii = 0; ii < 2; ++ii) {
                    int r  = ii * 16 + wave;
                    int rg = R0n + r; if (rg >= n_nodes) rg = n_nodes - 1;
                    gload_lds16(feat + (size_t)rg * IN_F + ((lane ^ (r & 7)) * 4),
                                &As[buf ^ 1][r * IN_F]);
                }
            }

            // compute tile t from As[buf] (A ds_reads + MFMA; B from regs)
            f32x4 acc = (f32x4){0.f, 0.f, 0.f, 0.f};
            const f32x4* ap = reinterpret_cast<const f32x4*>(&As[buf][arow * IN_F]);
            #pragma unroll
            for (int k0 = 0; k0 < 8; ++k0) {
                f32x4 a0 = ap[(k0 * 8 + 2 * q)     ^ (rr & 7)];
                f32x4 a1 = ap[(k0 * 8 + 2 * q + 1) ^ (rr & 7)];
                bf16x8 afr;
                afr[0] = (short)f2bf(a0[0]);
                afr[1] = (short)f2bf(a0[1]);
                afr[2] = (short)f2bf(a0[2]);
                afr[3] = (short)f2bf(a0[3]);
                afr[4] = (short)f2bf(a1[0]);
                afr[5] = (short)f2bf(a1[1]);
                afr[6] = (short)f2bf(a1[2]);
                afr[7] = (short)f2bf(a1[3]);
                acc = __builtin_amdgcn_mfma_f32_16x16x32_bf16(afr, bq[k0], acc, 0, 0, 0);
            }

            __syncthreads();   // next-tile stage complete + all waves done w/ As[buf]

            // exactly 4 unconditional scalar stores (h padded by BM rows)
            const int orow0 = t * BM + rowgrp * 16 + q * 4;
            const int col   = colgrp * 16 + rr;
            #pragma unroll
            for (int j = 0; j < 4; ++j)
                h[(size_t)(orow0 + j) * OUT_F + col] = f2bf(acc[j]);
            buf ^= 1;
        }
    }
}

// ---------------------------------------------------------------------------
// bin2: one block per bucket; local bhist scan -> e0, per-node counts,
// 128-wide scan -> rstart + norm, exact per-node CSR. (round-18 verbatim)
// ---------------------------------------------------------------------------
__global__ __launch_bounds__(256) void bin2_kernel(const unsigned* __restrict__ ebuf,
                                                   const int* __restrict__ bhist,
                                                   int* __restrict__ rstart,
                                                   float* __restrict__ norm,
                                                   int* __restrict__ eidx,
                                                   int n_nodes, int nbuck) {
    __shared__ int bs[MAXBUCK];
    __shared__ int lcnt[BNODES];
    __shared__ int lex[BNODES];
    __shared__ int sh[256];
    const int tid = threadIdx.x;
    const int node0 = blockIdx.x << BSH;

    {
        int v[4], s = 0;
        #pragma unroll
        for (int j = 0; j < 4; ++j) {
            int idx = tid * 4 + j;
            v[j] = (idx < nbuck) ? bhist[idx] : 0;
            s += v[j];
        }
        sh[tid] = s;
        __syncthreads();
        #pragma unroll
        for (int off = 1; off < 256; off <<= 1) {
            int t = (tid >= off) ? sh[tid - off] : 0;
            __syncthreads();
            sh[tid] += t;
            __syncthreads();
        }
        int ex = sh[tid] - s;
        #pragma unroll
        for (int j = 0; j < 4; ++j) {
            bs[tid * 4 + j] = ex;
            ex += v[j];
        }
    }
    __syncthreads();

    const int e0 = bs[blockIdx.x];
    const int e1 = e0 + bhist[blockIdx.x];

    if (tid < BNODES) lcnt[tid] = 0;
    __syncthreads();
    for (int e = e0 + tid; e < e1; e += 256)
        atomicAdd(&lcnt[ebuf[e] & (BNODES - 1)], 1);
    __syncthreads();

    int own = (tid < BNODES) ? lcnt[tid] : 0;
    if (tid < BNODES) lex[tid] = own;
    __syncthreads();
    #pragma unroll
    for (int off = 1; off < BNODES; off <<= 1) {
        int t = (tid >= off && tid < BNODES) ? lex[tid - off] : 0;
        __syncthreads();
        if (tid < BNODES) lex[tid] += t;
        __syncthreads();
    }
    if (tid < BNODES) {
        int ex = lex[tid] - own;
        lex[tid] = ex;
        int g = node0 + tid;
        if (g <= n_nodes) rstart[g] = e0 + ex;
        if (g < n_nodes) {
            float d = (float)own;
            if (d < 1.0f) d = 1.0f;
            norm[g] = 1.0f / sqrtf(d);
        }
        lcnt[tid] = 0;                 // reuse as cursor
    }
    __syncthreads();

    for (int e = e0 + tid; e < e1; e += 256) {
        unsigned pk = ebuf[e];
        int dl = pk & (BNODES - 1);
        int pos = atomicAdd(&lcnt[dl], 1);
        eidx[e0 + lex[dl] + pos] = (int)(pk >> BSH);
    }
}

// ---------------------------------------------------------------------------
// agg: one wave per dst node, 4 edge-slots x 16 lanes, uniform control flow.
// (unchanged — fabric-limited at ~64 us)
// ---------------------------------------------------------------------------
__global__ __launch_bounds__(256) void agg_kernel(const unsigned short* __restrict__ h,
                                                  const int* __restrict__ eidx,
                                                  const int* __restrict__ rstart,
                                                  const float* __restrict__ norm,
                                                  const float* __restrict__ bias,
                                                  float* __restrict__ out,
                                                  int n_nodes) {
    const int wave = threadIdx.x >> 6;
    const int lane = threadIdx.x & 63;
    const int grp  = lane >> 4;
    const int gl   = lane & 15;
    const int node = blockIdx.x * 4 + wave;
    if (node >= n_nodes) return;

    const int start = rstart[node];
    const int cnt   = rstart[node + 1] - start;
    const unsigned short* __restrict__ hb = h + gl * 8;

    float acc[8] = {0.f, 0.f, 0.f, 0.f, 0.f, 0.f, 0.f, 0.f};

    for (int base = 0; base < cnt; base += 64) {
        const int rem = min(64, cnt - base);
        int   ev = (lane < rem) ? eidx[start + base + lane] : 0;
        float nv = (lane < rem) ? norm[ev] : 0.f;

        int j = 0;
        for (; j + 16 <= rem; j += 16) {
            int   s0 = __shfl(ev, j + grp);
            int   s1 = __shfl(ev, j + grp + 4);
            int   s2 = __shfl(ev, j + grp + 8);
            int   s3 = __shfl(ev, j + grp + 12);
            float n0 = __shfl(nv, j + grp);
            float n1 = __shfl(nv, j + grp + 4);
            float n2 = __shfl(nv, j + grp + 8);
            float n3 = __shfl(nv, j + grp + 12);
            us8 v0 = *reinterpret_cast<const us8*>(hb + (size_t)s0 * OUT_F);
            us8 v1 = *reinterpret_cast<const us8*>(hb + (size_t)s1 * OUT_F);
            us8 v2 = *reinterpret_cast<const us8*>(hb + (size_t)s2 * OUT_F);
            us8 v3 = *reinterpret_cast<const us8*>(hb + (size_t)s3 * OUT_F);
            #pragma unroll
            for (int qq = 0; qq < 8; ++qq) {
                acc[qq] += bf2f(v0[qq]) * n0 + bf2f(v1[qq]) * n1
                         + bf2f(v2[qq]) * n2 + bf2f(v3[qq]) * n3;
            }
        }
        for (; j < rem; j += 4) {
            int   je = j + grp;
            int   jc = min(je, rem - 1);
            int   s  = __shfl(ev, jc);
            float nm = __shfl(nv, jc);
            if (je >= rem) nm = 0.f;
            us8 v = *reinterpret_cast<const us8*>(hb + (size_t)s * OUT_F);
            #pragma unroll
            for (int qq = 0; qq < 8; ++qq)
                acc[qq] += bf2f(v[qq]) * nm;
        }
    }

    #pragma unroll
    for (int qq = 0; qq < 8; ++qq) {
        acc[qq] += __shfl_xor(acc[qq], 16);
        acc[qq] += __shfl_xor(acc[qq], 32);
    }

    if (grp == 0) {
        const float nd = norm[node];
        const float4 b0 = *reinterpret_cast<const float4*>(bias + gl * 8);
        const float4 b1 = *reinterpret_cast<const float4*>(bias + gl * 8 + 4);
        float4 r0, r1;
        r0.x = acc[0] * nd + b0.x;
        r0.y = acc[1] * nd + b0.y;
        r0.z = acc[2] * nd + b0.z;
        r0.w = acc[3] * nd + b0.w;
        r1.x = acc[4] * nd + b1.x;
        r1.y = acc[5] * nd + b1.y;
        r1.z = acc[6] * nd + b1.z;
        r1.w = acc[7] * nd + b1.w;
        float* o = out + (size_t)node * OUT_F + gl * 8;
        *reinterpret_cast<float4*>(o)     = r0;
        *reinterpret_cast<float4*>(o + 4) = r1;
    }
}

// ---------------------------------------------------------------------------
extern "C" void kernel_launch(void* const* d_in, const int* in_sizes, int n_in,
                              void* d_out, int out_size, void* d_ws, size_t ws_size,
                              hipStream_t stream) {
    const float* feat   = (const float*)d_in[0];
    const float* weight = (const float*)d_in[1];
    const float* bias   = (const float*)d_in[2];
    const int*   src    = (const int*)d_in[3];
    const int*   dst    = (const int*)d_in[4];
    float* out = (float*)d_out;

    const int n_nodes = in_sizes[0] / IN_F;
    const int n_edges = in_sizes[3];
    const int nbuck   = (n_nodes + BNODES - 1) >> BSH;

    char* ws = (char*)d_ws;
    size_t off = 0;
    auto alloc = [&](size_t bytes) {
        char* p = ws + off;
        off += (bytes + 15) & ~(size_t)15;
        return p;
    };
    unsigned short* h  = (unsigned short*)alloc((size_t)(n_nodes + BM) * OUT_F * 2); // +BM pad rows
    float* norm        = (float*)alloc((size_t)n_nodes * 4);
    int*   rstart      = (int*)alloc(((size_t)n_nodes + 1) * 4);
    int*   bhist       = (int*)alloc(2 * MAXBUCK * 4);   // bhist | gcur0
    int*   gcur0       = bhist + MAXBUCK;
    int*   perbhist    = (int*)alloc((size_t)BIN1A_BLOCKS * MAXBUCK * 4);  // 1 MB
    unsigned short* Wt = (unsigned short*)alloc((size_t)OUT_F * IN_F * 2);
    unsigned* ebuf     = (unsigned*)alloc((size_t)n_edges * 4);
    int*   eidx        = (int*)alloc((size_t)n_edges * 4);

    hipMemsetAsync(bhist, 0, 2 * MAXBUCK * sizeof(int), stream);
    // K1: bin1a (+perbhist) || wprep
    prep_kernel<<<BIN1A_BLOCKS + OUT_F, 256, 0, stream>>>(weight, Wt, dst, bhist,
                                                          perbhist, n_edges, nbuck);
    // K2: bin1b (blocks 0..255, 12 KB) || gemm (blocks 256..511, 64 KB, B-regs)
    gemm_bin_kernel<<<BIN1B_BLOCKS + GEMM_BLOCKS, 1024, 0, stream>>>(
        feat, Wt, h, n_nodes, src, dst, bhist, perbhist, gcur0, ebuf,
        n_edges, nbuck);
    // K3: exact CSR
    bin2_kernel<<<nbuck, 256, 0, stream>>>(ebuf, bhist, rstart, norm, eidx,
                                           n_nodes, nbuck);
    // K4: aggregate
    agg_kernel<<<(n_nodes + 3) / 4, 256, 0, stream>>>(h, eidx, rstart, norm, bias, out, n_nodes);
}

// Round 23
// 146.750 us; speedup vs baseline: 1.0338x; 1.0338x over previous
//
#include <hip/hip_runtime.h>
#include <hip/hip_bf16.h>

#define IN_F 256
#define OUT_F 128
#define BSH 7
#define BNODES 128          // nodes per bucket = 1<<BSH
#define MAXBUCK 1024        // supports n_nodes <= 131072
#define BIN1A_BLOCKS 256
#define BIN1B_BLOCKS 256
#define GEMM_BLOCKS 256
#define BM 64               // gemm rows per tile (2 B-frags/wave -> 4x A re-read, was 8x)

typedef short bf16x8 __attribute__((ext_vector_type(8)));
typedef float f32x4 __attribute__((ext_vector_type(4)));
typedef unsigned short us8 __attribute__((ext_vector_type(8)));

__device__ __forceinline__ unsigned short f2bf(float x) {
    union { __hip_bfloat16 b; unsigned short u; } cv;
    cv.b = __float2bfloat16(x);
    return cv.u;
}
__device__ inline float bf2f(unsigned short x) {
    union { unsigned u; float f; } v; v.u = ((unsigned)x) << 16;
    return v.f;
}

// async 16B global -> LDS (DMA; wave-uniform LDS base + lane*16, per-lane gsrc)
__device__ __forceinline__ void gload_lds16(const void* g, void* l) {
    __builtin_amdgcn_global_load_lds(
        (const __attribute__((address_space(1))) unsigned int*)g,
        (__attribute__((address_space(3))) unsigned int*)l,
        16, 0, 0);
}

// ---------------------------------------------------------------------------
// K1 fused: blocks [0, BIN1A_BLOCKS) = bin1a (bucket histogram -> bhist AND
// per-block histogram row -> perbhist); blocks [BIN1A_BLOCKS,+128) = wprep.
// ---------------------------------------------------------------------------
__global__ __launch_bounds__(256) void prep_kernel(const float* __restrict__ W,
                                                   unsigned short* __restrict__ Wt,
                                                   const int* __restrict__ dst,
                                                   int* __restrict__ bhist,
                                                   int* __restrict__ perbhist,
                                                   int n_edges, int nbuck) {
    if ((int)blockIdx.x < BIN1A_BLOCKS) {
        __shared__ int hist[MAXBUCK];
        const int tid = threadIdx.x;
        const int chunk = (n_edges + BIN1A_BLOCKS - 1) / BIN1A_BLOCKS;
        const int lo = blockIdx.x * chunk;
        const int hi = min(lo + chunk, n_edges);

        for (int i = tid; i < MAXBUCK; i += 256) hist[i] = 0;
        __syncthreads();
        for (int e = lo + tid; e < hi; e += 256)
            atomicAdd(&hist[dst[e] >> BSH], 1);
        __syncthreads();
        int* myrow = perbhist + (size_t)blockIdx.x * MAXBUCK;
        for (int i = tid; i < nbuck; i += 256) {
            int c = hist[i];
            myrow[i] = c;
            if (c) atomicAdd(&bhist[i], c);
        }
    } else {
        int n = blockIdx.x - BIN1A_BLOCKS;   // 0..127
        int k = threadIdx.x;                 // 0..255
        Wt[n * IN_F + k] = f2bf(W[k * OUT_F + n]);
    }
}

// ---------------------------------------------------------------------------
// bin1b (1024 thr, standalone — fusion with big-LDS gemm failed 3x, banned):
// local LDS scan of bhist -> bucket prefix; per-block counts from perbhist;
// reserve via gcur0; single placement pass into bucket-grouped ebuf.
// ---------------------------------------------------------------------------
__global__ __launch_bounds__(1024) void bin1b_kernel(const int* __restrict__ src,
                                                     const int* __restrict__ dst,
                                                     const int* __restrict__ bhist,
                                                     const int* __restrict__ perbhist,
                                                     int* __restrict__ gcur0,
                                                     unsigned* __restrict__ ebuf,
                                                     int n_edges, int nbuck) {
    __shared__ int scanv[MAXBUCK];
    __shared__ int hist[MAXBUCK];
    __shared__ int lbase[MAXBUCK];
    const int tid = threadIdx.x;
    const int chunk = (n_edges + BIN1B_BLOCKS - 1) / BIN1B_BLOCKS;
    const int lo = blockIdx.x * chunk;
    const int hi = min(lo + chunk, n_edges);

    int own = (tid < nbuck) ? bhist[tid] : 0;
    scanv[tid] = own;
    __syncthreads();
    #pragma unroll
    for (int off = 1; off < MAXBUCK; off <<= 1) {
        int t = (tid >= off) ? scanv[tid - off] : 0;
        __syncthreads();
        scanv[tid] += t;
        __syncthreads();
    }
    int bstart_t = scanv[tid] - own;   // exclusive
    __syncthreads();
    scanv[tid] = bstart_t;
    __syncthreads();

    if (tid < nbuck) {
        int c = perbhist[(size_t)blockIdx.x * MAXBUCK + tid];
        lbase[tid] = (c > 0) ? (scanv[tid] + atomicAdd(&gcur0[tid], c)) : 0;
        hist[tid] = 0;                 // local cursor
    }
    __syncthreads();
    for (int e = lo + tid; e < hi; e += 1024) {
        int d = dst[e];
        int bkt = d >> BSH;
        int off = atomicAdd(&hist[bkt], 1);
        ebuf[lbase[bkt] + off] = ((unsigned)src[e] << BSH) | (unsigned)(d & (BNODES - 1));
    }
}

// ---------------------------------------------------------------------------
// gemm: h = bf16( feat @ W ), persistent 2-deep async pipeline, 1024 thr.
// BM=64: wave roles rowgrp(4 x 16 rows) x colpair(4 x 32 cols). Each wave
// holds TWO B-fragment sets in registers (bq0/bq1, 64 VGPR) and does 2 MFMA
// per A-read -> the A tile is re-read from LDS only 4x (was 8x): LDS-read
// traffic per row halves (the computed ~1.3us/tile LDS floor was matching
// the stubborn ~42us). As[2] x 64 KB = 128 KB, 1 block/CU, 16 waves.
// Swizzle unchanged: chunk c of row r at c^(r&7); arow&7 == rr&7.
// ---------------------------------------------------------------------------
__global__ __launch_bounds__(1024) void gemm_mfma(const float* __restrict__ feat,
                                                  const unsigned short* __restrict__ Wt,
                                                  unsigned short* __restrict__ h,
                                                  int n_nodes) {
    __shared__ float As[2][BM * IN_F];            // 2 x 64 KB = 128 KB

    const int tid  = threadIdx.x;
    const int wave = tid >> 6;          // 0..15
    const int lane = tid & 63;
    const int q    = lane >> 4;         // 0..3
    const int rr   = lane & 15;
    const int rowgrp  = wave & 3;       // 4 x 16-row groups
    const int colpair = wave >> 2;      // 4 x 32-col pairs

    const int ntiles = (n_nodes + BM - 1) / BM;
    const int nit = ((int)blockIdx.x < ntiles)
                  ? ((ntiles - (int)blockIdx.x + GEMM_BLOCKS - 1) / GEMM_BLOCKS) : 0;

    const int brow0 = colpair * 32 + rr;
    const int brow1 = colpair * 32 + 16 + rr;

    // ---- B fragments -> registers, once (L2-hot Wt) ----
    bf16x8 bq0[8], bq1[8];
    #pragma unroll
    for (int k0 = 0; k0 < 8; ++k0) {
        bq0[k0] = *reinterpret_cast<const bf16x8*>(
            Wt + (size_t)brow0 * IN_F + (k0 * 4 + q) * 8);
        bq1[k0] = *reinterpret_cast<const bf16x8*>(
            Wt + (size_t)brow1 * IN_F + (k0 * 4 + q) * 8);
    }

    // ---- prologue: stage tile 0 (4 rows/wave: r = ii*16 + wave) ----
    if (0 < nit) {
        const int R0 = (int)blockIdx.x * BM;
        #pragma unroll
        for (int ii = 0; ii < 4; ++ii) {
            int r  = ii * 16 + wave;         // 0..63
            int rg = R0 + r; if (rg >= n_nodes) rg = n_nodes - 1;
            gload_lds16(feat + (size_t)rg * IN_F + ((lane ^ (r & 7)) * 4),
                        &As[0][r * IN_F]);
        }
    }
    __syncthreads();

    const int arow = rowgrp * 16 + rr;

    int t = (int)blockIdx.x, buf = 0;
    for (int i = 0; i < nit; ++i, t += GEMM_BLOCKS) {
        // issue stage of tile i+1 into the other buffer
        if (i + 1 < nit) {
            const int R0n = (t + GEMM_BLOCKS) * BM;
            #pragma unroll
            for (int ii = 0; ii < 4; ++ii) {
                int r  = ii * 16 + wave;
                int rg = R0n + r; if (rg >= n_nodes) rg = n_nodes - 1;
                gload_lds16(feat + (size_t)rg * IN_F + ((lane ^ (r & 7)) * 4),
                            &As[buf ^ 1][r * IN_F]);
            }
        }

        // compute tile t from As[buf]: per k-step 2 A-reads, 2 MFMAs
        f32x4 acc0 = (f32x4){0.f, 0.f, 0.f, 0.f};
        f32x4 acc1 = (f32x4){0.f, 0.f, 0.f, 0.f};
        const f32x4* ap = reinterpret_cast<const f32x4*>(&As[buf][arow * IN_F]);
        #pragma unroll
        for (int k0 = 0; k0 < 8; ++k0) {
            f32x4 a0 = ap[(k0 * 8 + 2 * q)     ^ (rr & 7)];
            f32x4 a1 = ap[(k0 * 8 + 2 * q + 1) ^ (rr & 7)];
            bf16x8 afr;
            afr[0] = (short)f2bf(a0[0]);
            afr[1] = (short)f2bf(a0[1]);
            afr[2] = (short)f2bf(a0[2]);
            afr[3] = (short)f2bf(a0[3]);
            afr[4] = (short)f2bf(a1[0]);
            afr[5] = (short)f2bf(a1[1]);
            afr[6] = (short)f2bf(a1[2]);
            afr[7] = (short)f2bf(a1[3]);
            acc0 = __builtin_amdgcn_mfma_f32_16x16x32_bf16(afr, bq0[k0], acc0, 0, 0, 0);
            acc1 = __builtin_amdgcn_mfma_f32_16x16x32_bf16(afr, bq1[k0], acc1, 0, 0, 0);
        }

        __syncthreads();   // next-tile stage complete + all waves done w/ As[buf]

        // 8 unconditional scalar stores (h padded by BM rows)
        const int orow0 = t * BM + rowgrp * 16 + q * 4;
        const int col0  = colpair * 32 + rr;
        const int col1  = colpair * 32 + 16 + rr;
        #pragma unroll
        for (int j = 0; j < 4; ++j) {
            h[(size_t)(orow0 + j) * OUT_F + col0] = f2bf(acc0[j]);
            h[(size_t)(orow0 + j) * OUT_F + col1] = f2bf(acc1[j]);
        }
        buf ^= 1;
    }
}

// ---------------------------------------------------------------------------
// bin2: one block per bucket; local bhist scan -> e0, per-node counts,
// 128-wide scan -> rstart + norm, exact per-node CSR. (round-18 verbatim)
// ---------------------------------------------------------------------------
__global__ __launch_bounds__(256) void bin2_kernel(const unsigned* __restrict__ ebuf,
                                                   const int* __restrict__ bhist,
                                                   int* __restrict__ rstart,
                                                   float* __restrict__ norm,
                                                   int* __restrict__ eidx,
                                                   int n_nodes, int nbuck) {
    __shared__ int bs[MAXBUCK];
    __shared__ int lcnt[BNODES];
    __shared__ int lex[BNODES];
    __shared__ int sh[256];
    const int tid = threadIdx.x;
    const int node0 = blockIdx.x << BSH;

    {
        int v[4], s = 0;
        #pragma unroll
        for (int j = 0; j < 4; ++j) {
            int idx = tid * 4 + j;
            v[j] = (idx < nbuck) ? bhist[idx] : 0;
            s += v[j];
        }
        sh[tid] = s;
        __syncthreads();
        #pragma unroll
        for (int off = 1; off < 256; off <<= 1) {
            int t = (tid >= off) ? sh[tid - off] : 0;
            __syncthreads();
            sh[tid] += t;
            __syncthreads();
        }
        int ex = sh[tid] - s;
        #pragma unroll
        for (int j = 0; j < 4; ++j) {
            bs[tid * 4 + j] = ex;
            ex += v[j];
        }
    }
    __syncthreads();

    const int e0 = bs[blockIdx.x];
    const int e1 = e0 + bhist[blockIdx.x];

    if (tid < BNODES) lcnt[tid] = 0;
    __syncthreads();
    for (int e = e0 + tid; e < e1; e += 256)
        atomicAdd(&lcnt[ebuf[e] & (BNODES - 1)], 1);
    __syncthreads();

    int own = (tid < BNODES) ? lcnt[tid] : 0;
    if (tid < BNODES) lex[tid] = own;
    __syncthreads();
    #pragma unroll
    for (int off = 1; off < BNODES; off <<= 1) {
        int t = (tid >= off && tid < BNODES) ? lex[tid - off] : 0;
        __syncthreads();
        if (tid < BNODES) lex[tid] += t;
        __syncthreads();
    }
    if (tid < BNODES) {
        int ex = lex[tid] - own;
        lex[tid] = ex;
        int g = node0 + tid;
        if (g <= n_nodes) rstart[g] = e0 + ex;
        if (g < n_nodes) {
            float d = (float)own;
            if (d < 1.0f) d = 1.0f;
            norm[g] = 1.0f / sqrtf(d);
        }
        lcnt[tid] = 0;                 // reuse as cursor
    }
    __syncthreads();

    for (int e = e0 + tid; e < e1; e += 256) {
        unsigned pk = ebuf[e];
        int dl = pk & (BNODES - 1);
        int pos = atomicAdd(&lcnt[dl], 1);
        eidx[e0 + lex[dl] + pos] = (int)(pk >> BSH);
    }
}

// ---------------------------------------------------------------------------
// agg: one wave per dst node, 4 edge-slots x 16 lanes, uniform control flow.
// (unchanged — fabric-limited at ~64 us)
// ---------------------------------------------------------------------------
__global__ __launch_bounds__(256) void agg_kernel(const unsigned short* __restrict__ h,
                                                  const int* __restrict__ eidx,
                                                  const int* __restrict__ rstart,
                                                  const float* __restrict__ norm,
                                                  const float* __restrict__ bias,
                                                  float* __restrict__ out,
                                                  int n_nodes) {
    const int wave = threadIdx.x >> 6;
    const int lane = threadIdx.x & 63;
    const int grp  = lane >> 4;
    const int gl   = lane & 15;
    const int node = blockIdx.x * 4 + wave;
    if (node >= n_nodes) return;

    const int start = rstart[node];
    const int cnt   = rstart[node + 1] - start;
    const unsigned short* __restrict__ hb = h + gl * 8;

    float acc[8] = {0.f, 0.f, 0.f, 0.f, 0.f, 0.f, 0.f, 0.f};

    for (int base = 0; base < cnt; base += 64) {
        const int rem = min(64, cnt - base);
        int   ev = (lane < rem) ? eidx[start + base + lane] : 0;
        float nv = (lane < rem) ? norm[ev] : 0.f;

        int j = 0;
        for (; j + 16 <= rem; j += 16) {
            int   s0 = __shfl(ev, j + grp);
            int   s1 = __shfl(ev, j + grp + 4);
            int   s2 = __shfl(ev, j + grp + 8);
            int   s3 = __shfl(ev, j + grp + 12);
            float n0 = __shfl(nv, j + grp);
            float n1 = __shfl(nv, j + grp + 4);
            float n2 = __shfl(nv, j + grp + 8);
            float n3 = __shfl(nv, j + grp + 12);
            us8 v0 = *reinterpret_cast<const us8*>(hb + (size_t)s0 * OUT_F);
            us8 v1 = *reinterpret_cast<const us8*>(hb + (size_t)s1 * OUT_F);
            us8 v2 = *reinterpret_cast<const us8*>(hb + (size_t)s2 * OUT_F);
            us8 v3 = *reinterpret_cast<const us8*>(hb + (size_t)s3 * OUT_F);
            #pragma unroll
            for (int qq = 0; qq < 8; ++qq) {
                acc[qq] += bf2f(v0[qq]) * n0 + bf2f(v1[qq]) * n1
                         + bf2f(v2[qq]) * n2 + bf2f(v3[qq]) * n3;
            }
        }
        for (; j < rem; j += 4) {
            int   je = j + grp;
            int   jc = min(je, rem - 1);
            int   s  = __shfl(ev, jc);
            float nm = __shfl(nv, jc);
            if (je >= rem) nm = 0.f;
            us8 v = *reinterpret_cast<const us8*>(hb + (size_t)s * OUT_F);
            #pragma unroll
            for (int qq = 0; qq < 8; ++qq)
                acc[qq] += bf2f(v[qq]) * nm;
        }
    }

    #pragma unroll
    for (int qq = 0; qq < 8; ++qq) {
        acc[qq] += __shfl_xor(acc[qq], 16);
        acc[qq] += __shfl_xor(acc[qq], 32);
    }

    if (grp == 0) {
        const float nd = norm[node];
        const float4 b0 = *reinterpret_cast<const float4*>(bias + gl * 8);
        const float4 b1 = *reinterpret_cast<const float4*>(bias + gl * 8 + 4);
        float4 r0, r1;
        r0.x = acc[0] * nd + b0.x;
        r0.y = acc[1] * nd + b0.y;
        r0.z = acc[2] * nd + b0.z;
        r0.w = acc[3] * nd + b0.w;
        r1.x = acc[4] * nd + b1.x;
        r1.y = acc[5] * nd + b1.y;
        r1.z = acc[6] * nd + b1.z;
        r1.w = acc[7] * nd + b1.w;
        float* o = out + (size_t)node * OUT_F + gl * 8;
        *reinterpret_cast<float4*>(o)     = r0;
        *reinterpret_cast<float4*>(o + 4) = r1;
    }
}

// ---------------------------------------------------------------------------
extern "C" void kernel_launch(void* const* d_in, const int* in_sizes, int n_in,
                              void* d_out, int out_size, void* d_ws, size_t ws_size,
                              hipStream_t stream) {
    const float* feat   = (const float*)d_in[0];
    const float* weight = (const float*)d_in[1];
    const float* bias   = (const float*)d_in[2];
    const int*   src    = (const int*)d_in[3];
    const int*   dst    = (const int*)d_in[4];
    float* out = (float*)d_out;

    const int n_nodes = in_sizes[0] / IN_F;
    const int n_edges = in_sizes[3];
    const int nbuck   = (n_nodes + BNODES - 1) >> BSH;

    char* ws = (char*)d_ws;
    size_t off = 0;
    auto alloc = [&](size_t bytes) {
        char* p = ws + off;
        off += (bytes + 15) & ~(size_t)15;
        return p;
    };
    unsigned short* h  = (unsigned short*)alloc((size_t)(n_nodes + BM) * OUT_F * 2); // +BM pad rows
    float* norm        = (float*)alloc((size_t)n_nodes * 4);
    int*   rstart      = (int*)alloc(((size_t)n_nodes + 1) * 4);
    int*   bhist       = (int*)alloc(2 * MAXBUCK * 4);   // bhist | gcur0
    int*   gcur0       = bhist + MAXBUCK;
    int*   perbhist    = (int*)alloc((size_t)BIN1A_BLOCKS * MAXBUCK * 4);  // 1 MB
    unsigned short* Wt = (unsigned short*)alloc((size_t)OUT_F * IN_F * 2);
    unsigned* ebuf     = (unsigned*)alloc((size_t)n_edges * 4);
    int*   eidx        = (int*)alloc((size_t)n_edges * 4);

    hipMemsetAsync(bhist, 0, 2 * MAXBUCK * sizeof(int), stream);
    // K1: bin1a (+perbhist) || wprep
    prep_kernel<<<BIN1A_BLOCKS + OUT_F, 256, 0, stream>>>(weight, Wt, dst, bhist,
                                                          perbhist, n_edges, nbuck);
    // K2: gemm (BM=64, 2 B-frags/wave, 2-deep pipeline, 128 KB LDS)
    gemm_mfma<<<GEMM_BLOCKS, 1024, 0, stream>>>(feat, Wt, h, n_nodes);
    // K3: binning into bucket-grouped ebuf
    bin1b_kernel<<<BIN1B_BLOCKS, 1024, 0, stream>>>(src, dst, bhist, perbhist,
                                                    gcur0, ebuf, n_edges, nbuck);
    // K4: exact CSR
    bin2_kernel<<<nbuck, 256, 0, stream>>>(ebuf, bhist, rstart, norm, eidx,
                                           n_nodes, nbuck);
    // K5: aggregate
    agg_kernel<<<(n_nodes + 3) / 4, 256, 0, stream>>>(h, eidx, rstart, norm, bias, out, n_nodes);
}

// Round 24
// 145.034 us; speedup vs baseline: 1.0460x; 1.0118x over previous
//
#include <hip/hip_runtime.h>
#include <hip/hip_bf16.h>

#define IN_F 256
#define OUT_F 128
#define BSH 7
#define BNODES 128          // nodes per bucket = 1<<BSH
#define MAXBUCK 1024        // supports n_nodes <= 131072
#define BIN1A_BLOCKS 256
#define BIN1B_BLOCKS 256
#define GEMM_BLOCKS 256
#define BM 32               // gemm rows per tile (round-20 optimum)

typedef short bf16x8 __attribute__((ext_vector_type(8)));
typedef float f32x4 __attribute__((ext_vector_type(4)));
typedef unsigned short us8 __attribute__((ext_vector_type(8)));

__device__ __forceinline__ unsigned short f2bf(float x) {
    union { __hip_bfloat16 b; unsigned short u; } cv;
    cv.b = __float2bfloat16(x);
    return cv.u;
}
__device__ inline float bf2f(unsigned short x) {
    union { unsigned u; float f; } v; v.u = ((unsigned)x) << 16;
    return v.f;
}

// async 16B global -> LDS (DMA; wave-uniform LDS base + lane*16, per-lane gsrc)
__device__ __forceinline__ void gload_lds16(const void* g, void* l) {
    __builtin_amdgcn_global_load_lds(
        (const __attribute__((address_space(1))) unsigned int*)g,
        (__attribute__((address_space(3))) unsigned int*)l,
        16, 0, 0);
}

// ---------------------------------------------------------------------------
// K1 fused: blocks [0, BIN1A_BLOCKS) = bin1a (bucket histogram -> bhist AND
// per-block histogram row -> perbhist); blocks [BIN1A_BLOCKS,+128) = wprep.
// ---------------------------------------------------------------------------
__global__ __launch_bounds__(256) void prep_kernel(const float* __restrict__ W,
                                                   unsigned short* __restrict__ Wt,
                                                   const int* __restrict__ dst,
                                                   int* __restrict__ bhist,
                                                   int* __restrict__ perbhist,
                                                   int n_edges, int nbuck) {
    if ((int)blockIdx.x < BIN1A_BLOCKS) {
        __shared__ int hist[MAXBUCK];
        const int tid = threadIdx.x;
        const int chunk = (n_edges + BIN1A_BLOCKS - 1) / BIN1A_BLOCKS;
        const int lo = blockIdx.x * chunk;
        const int hi = min(lo + chunk, n_edges);

        for (int i = tid; i < MAXBUCK; i += 256) hist[i] = 0;
        __syncthreads();
        for (int e = lo + tid; e < hi; e += 256)
            atomicAdd(&hist[dst[e] >> BSH], 1);
        __syncthreads();
        int* myrow = perbhist + (size_t)blockIdx.x * MAXBUCK;
        for (int i = tid; i < nbuck; i += 256) {
            int c = hist[i];
            myrow[i] = c;
            if (c) atomicAdd(&bhist[i], c);
        }
    } else {
        int n = blockIdx.x - BIN1A_BLOCKS;   // 0..127
        int k = threadIdx.x;                 // 0..255
        Wt[n * IN_F + k] = f2bf(W[k * OUT_F + n]);
    }
}

// ---------------------------------------------------------------------------
// bin1b (1024 thr): local LDS scan of bhist -> bucket prefix; per-block
// counts from perbhist; reserve via gcur0; single placement pass.
// ---------------------------------------------------------------------------
__global__ __launch_bounds__(1024) void bin1b_kernel(const int* __restrict__ src,
                                                     const int* __restrict__ dst,
                                                     const int* __restrict__ bhist,
                                                     const int* __restrict__ perbhist,
                                                     int* __restrict__ gcur0,
                                                     unsigned* __restrict__ ebuf,
                                                     int n_edges, int nbuck) {
    __shared__ int scanv[MAXBUCK];
    __shared__ int hist[MAXBUCK];
    __shared__ int lbase[MAXBUCK];
    const int tid = threadIdx.x;
    const int chunk = (n_edges + BIN1B_BLOCKS - 1) / BIN1B_BLOCKS;
    const int lo = blockIdx.x * chunk;
    const int hi = min(lo + chunk, n_edges);

    int own = (tid < nbuck) ? bhist[tid] : 0;
    scanv[tid] = own;
    __syncthreads();
    #pragma unroll
    for (int off = 1; off < MAXBUCK; off <<= 1) {
        int t = (tid >= off) ? scanv[tid - off] : 0;
        __syncthreads();
        scanv[tid] += t;
        __syncthreads();
    }
    int bstart_t = scanv[tid] - own;   // exclusive
    __syncthreads();
    scanv[tid] = bstart_t;
    __syncthreads();

    if (tid < nbuck) {
        int c = perbhist[(size_t)blockIdx.x * MAXBUCK + tid];
        lbase[tid] = (c > 0) ? (scanv[tid] + atomicAdd(&gcur0[tid], c)) : 0;
        hist[tid] = 0;                 // local cursor
    }
    __syncthreads();
    for (int e = lo + tid; e < hi; e += 1024) {
        int d = dst[e];
        int bkt = d >> BSH;
        int off = atomicAdd(&hist[bkt], 1);
        ebuf[lbase[bkt] + off] = ((unsigned)src[e] << BSH) | (unsigned)(d & (BNODES - 1));
    }
}

// ---------------------------------------------------------------------------
// gemm: h = bf16( feat @ W ), persistent 3-deep async pipeline, 1024 thr,
// B entirely in registers (32 VGPR/wave), LDS = As[3] x 32 KB = 96 KB.
// (round-20 optimum configuration, verbatim)
// ---------------------------------------------------------------------------
__global__ __launch_bounds__(1024) void gemm_mfma(const float* __restrict__ feat,
                                                  const unsigned short* __restrict__ Wt,
                                                  unsigned short* __restrict__ h,
                                                  int n_nodes) {
    __shared__ float As[3][BM * IN_F];            // 3 x 32 KB = 96 KB

    const int tid  = threadIdx.x;
    const int wave = tid >> 6;          // 0..15
    const int lane = tid & 63;
    const int q    = lane >> 4;         // 0..3
    const int rr   = lane & 15;
    const int rowgrp = wave & 1;
    const int colgrp = wave >> 1;

    const int ntiles = (n_nodes + BM - 1) / BM;
    const int nit = ((int)blockIdx.x < ntiles)
                  ? ((ntiles - (int)blockIdx.x + GEMM_BLOCKS - 1) / GEMM_BLOCKS) : 0;

    const int brow = colgrp * 16 + rr;

    // B fragments -> registers, once (L2-hot Wt)
    bf16x8 bq[8];
    #pragma unroll
    for (int k0 = 0; k0 < 8; ++k0)
        bq[k0] = *reinterpret_cast<const bf16x8*>(
            Wt + (size_t)brow * IN_F + (k0 * 4 + q) * 8);

    // prologue: stage tiles 0 and 1
    #pragma unroll
    for (int pb = 0; pb < 2; ++pb) {
        if (pb < nit) {
            const int R0 = ((int)blockIdx.x + pb * GEMM_BLOCKS) * BM;
            #pragma unroll
            for (int ii = 0; ii < 2; ++ii) {
                int r  = ii * 16 + wave;
                int rg = R0 + r; if (rg >= n_nodes) rg = n_nodes - 1;
                gload_lds16(feat + (size_t)rg * IN_F + ((lane ^ (r & 7)) * 4),
                            &As[pb][r * IN_F]);
            }
        }
    }

    const int arow = rowgrp * 16 + rr;

    int t = (int)blockIdx.x;
    for (int i = 0; i < nit; ++i, t += GEMM_BLOCKS) {
        if (nit < 4)          asm volatile("s_waitcnt vmcnt(0)" ::: "memory");
        else if (i == 0)      asm volatile("s_waitcnt vmcnt(2)" ::: "memory");
        else if (i == 1)      asm volatile("s_waitcnt vmcnt(6)" ::: "memory");
        else if (i < nit - 1) asm volatile("s_waitcnt vmcnt(10)" ::: "memory");
        else                  asm volatile("s_waitcnt vmcnt(8)" ::: "memory");
        __builtin_amdgcn_s_barrier();

        // issue stage of tile i+2 into the buffer freed at iter i-1
        if (i + 2 < nit) {
            const int R0n = (t + 2 * GEMM_BLOCKS) * BM;
            float* dbuf = As[(i + 2) % 3];
            #pragma unroll
            for (int ii = 0; ii < 2; ++ii) {
                int r  = ii * 16 + wave;
                int rg = R0n + r; if (rg >= n_nodes) rg = n_nodes - 1;
                gload_lds16(feat + (size_t)rg * IN_F + ((lane ^ (r & 7)) * 4),
                            &dbuf[r * IN_F]);
            }
        }

        // compute tile t from As[i%3] (A ds_reads + MFMA; B from regs)
        f32x4 acc = (f32x4){0.f, 0.f, 0.f, 0.f};
        const f32x4* ap = reinterpret_cast<const f32x4*>(&As[i % 3][arow * IN_F]);
        #pragma unroll
        for (int k0 = 0; k0 < 8; ++k0) {
            f32x4 a0 = ap[(k0 * 8 + 2 * q)     ^ (rr & 7)];
            f32x4 a1 = ap[(k0 * 8 + 2 * q + 1) ^ (rr & 7)];
            bf16x8 afr;
            afr[0] = (short)f2bf(a0[0]);
            afr[1] = (short)f2bf(a0[1]);
            afr[2] = (short)f2bf(a0[2]);
            afr[3] = (short)f2bf(a0[3]);
            afr[4] = (short)f2bf(a1[0]);
            afr[5] = (short)f2bf(a1[1]);
            afr[6] = (short)f2bf(a1[2]);
            afr[7] = (short)f2bf(a1[3]);
            acc = __builtin_amdgcn_mfma_f32_16x16x32_bf16(afr, bq[k0], acc, 0, 0, 0);
        }

        // exactly 4 unconditional scalar stores (h padded by BM rows)
        const int orow0 = t * BM + rowgrp * 16 + q * 4;
        const int col   = colgrp * 16 + rr;
        #pragma unroll
        for (int j = 0; j < 4; ++j)
            h[(size_t)(orow0 + j) * OUT_F + col] = f2bf(acc[j]);
    }
}

// ---------------------------------------------------------------------------
// bin2: one block per bucket; local bhist scan -> e0, per-node counts,
// 128-wide scan -> rstart + norm, exact per-node CSR.
// ---------------------------------------------------------------------------
__global__ __launch_bounds__(256) void bin2_kernel(const unsigned* __restrict__ ebuf,
                                                   const int* __restrict__ bhist,
                                                   int* __restrict__ rstart,
                                                   float* __restrict__ norm,
                                                   int* __restrict__ eidx,
                                                   int n_nodes, int nbuck) {
    __shared__ int bs[MAXBUCK];
    __shared__ int lcnt[BNODES];
    __shared__ int lex[BNODES];
    __shared__ int sh[256];
    const int tid = threadIdx.x;
    const int node0 = blockIdx.x << BSH;

    {
        int v[4], s = 0;
        #pragma unroll
        for (int j = 0; j < 4; ++j) {
            int idx = tid * 4 + j;
            v[j] = (idx < nbuck) ? bhist[idx] : 0;
            s += v[j];
        }
        sh[tid] = s;
        __syncthreads();
        #pragma unroll
        for (int off = 1; off < 256; off <<= 1) {
            int t = (tid >= off) ? sh[tid - off] : 0;
            __syncthreads();
            sh[tid] += t;
            __syncthreads();
        }
        int ex = sh[tid] - s;
        #pragma unroll
        for (int j = 0; j < 4; ++j) {
            bs[tid * 4 + j] = ex;
            ex += v[j];
        }
    }
    __syncthreads();

    const int e0 = bs[blockIdx.x];
    const int e1 = e0 + bhist[blockIdx.x];

    if (tid < BNODES) lcnt[tid] = 0;
    __syncthreads();
    for (int e = e0 + tid; e < e1; e += 256)
        atomicAdd(&lcnt[ebuf[e] & (BNODES - 1)], 1);
    __syncthreads();

    int own = (tid < BNODES) ? lcnt[tid] : 0;
    if (tid < BNODES) lex[tid] = own;
    __syncthreads();
    #pragma unroll
    for (int off = 1; off < BNODES; off <<= 1) {
        int t = (tid >= off && tid < BNODES) ? lex[tid - off] : 0;
        __syncthreads();
        if (tid < BNODES) lex[tid] += t;
        __syncthreads();
    }
    if (tid < BNODES) {
        int ex = lex[tid] - own;
        lex[tid] = ex;
        int g = node0 + tid;
        if (g <= n_nodes) rstart[g] = e0 + ex;
        if (g < n_nodes) {
            float d = (float)own;
            if (d < 1.0f) d = 1.0f;
            norm[g] = 1.0f / sqrtf(d);
        }
        lcnt[tid] = 0;                 // reuse as cursor
    }
    __syncthreads();

    for (int e = e0 + tid; e < e1; e += 256) {
        unsigned pk = ebuf[e];
        int dl = pk & (BNODES - 1);
        int pos = atomicAdd(&lcnt[dl], 1);
        eidx[e0 + lex[dl] + pos] = (int)(pk >> BSH);
    }
}

// ---------------------------------------------------------------------------
// agg: one wave per dst node, 4 edge-slots x 16 lanes, uniform control flow.
// (fabric-limited at ~64 us — structural)
// ---------------------------------------------------------------------------
__global__ __launch_bounds__(256) void agg_kernel(const unsigned short* __restrict__ h,
                                                  const int* __restrict__ eidx,
                                                  const int* __restrict__ rstart,
                                                  const float* __restrict__ norm,
                                                  const float* __restrict__ bias,
                                                  float* __restrict__ out,
                                                  int n_nodes) {
    const int wave = threadIdx.x >> 6;
    const int lane = threadIdx.x & 63;
    const int grp  = lane >> 4;
    const int gl   = lane & 15;
    const int node = blockIdx.x * 4 + wave;
    if (node >= n_nodes) return;

    const int start = rstart[node];
    const int cnt   = rstart[node + 1] - start;
    const unsigned short* __restrict__ hb = h + gl * 8;

    float acc[8] = {0.f, 0.f, 0.f, 0.f, 0.f, 0.f, 0.f, 0.f};

    for (int base = 0; base < cnt; base += 64) {
        const int rem = min(64, cnt - base);
        int   ev = (lane < rem) ? eidx[start + base + lane] : 0;
        float nv = (lane < rem) ? norm[ev] : 0.f;

        int j = 0;
        for (; j + 16 <= rem; j += 16) {
            int   s0 = __shfl(ev, j + grp);
            int   s1 = __shfl(ev, j + grp + 4);
            int   s2 = __shfl(ev, j + grp + 8);
            int   s3 = __shfl(ev, j + grp + 12);
            float n0 = __shfl(nv, j + grp);
            float n1 = __shfl(nv, j + grp + 4);
            float n2 = __shfl(nv, j + grp + 8);
            float n3 = __shfl(nv, j + grp + 12);
            us8 v0 = *reinterpret_cast<const us8*>(hb + (size_t)s0 * OUT_F);
            us8 v1 = *reinterpret_cast<const us8*>(hb + (size_t)s1 * OUT_F);
            us8 v2 = *reinterpret_cast<const us8*>(hb + (size_t)s2 * OUT_F);
            us8 v3 = *reinterpret_cast<const us8*>(hb + (size_t)s3 * OUT_F);
            #pragma unroll
            for (int qq = 0; qq < 8; ++qq) {
                acc[qq] += bf2f(v0[qq]) * n0 + bf2f(v1[qq]) * n1
                         + bf2f(v2[qq]) * n2 + bf2f(v3[qq]) * n3;
            }
        }
        for (; j < rem; j += 4) {
            int   je = j + grp;
            int   jc = min(je, rem - 1);
            int   s  = __shfl(ev, jc);
            float nm = __shfl(nv, jc);
            if (je >= rem) nm = 0.f;
            us8 v = *reinterpret_cast<const us8*>(hb + (size_t)s * OUT_F);
            #pragma unroll
            for (int qq = 0; qq < 8; ++qq)
                acc[qq] += bf2f(v[qq]) * nm;
        }
    }

    #pragma unroll
    for (int qq = 0; qq < 8; ++qq) {
        acc[qq] += __shfl_xor(acc[qq], 16);
        acc[qq] += __shfl_xor(acc[qq], 32);
    }

    if (grp == 0) {
        const float nd = norm[node];
        const float4 b0 = *reinterpret_cast<const float4*>(bias + gl * 8);
        const float4 b1 = *reinterpret_cast<const float4*>(bias + gl * 8 + 4);
        float4 r0, r1;
        r0.x = acc[0] * nd + b0.x;
        r0.y = acc[1] * nd + b0.y;
        r0.z = acc[2] * nd + b0.z;
        r0.w = acc[3] * nd + b0.w;
        r1.x = acc[4] * nd + b1.x;
        r1.y = acc[5] * nd + b1.y;
        r1.z = acc[6] * nd + b1.z;
        r1.w = acc[7] * nd + b1.w;
        float* o = out + (size_t)node * OUT_F + gl * 8;
        *reinterpret_cast<float4*>(o)     = r0;
        *reinterpret_cast<float4*>(o + 4) = r1;
    }
}

// ---------------------------------------------------------------------------
extern "C" void kernel_launch(void* const* d_in, const int* in_sizes, int n_in,
                              void* d_out, int out_size, void* d_ws, size_t ws_size,
                              hipStream_t stream) {
    const float* feat   = (const float*)d_in[0];
    const float* weight = (const float*)d_in[1];
    const float* bias   = (const float*)d_in[2];
    const int*   src    = (const int*)d_in[3];
    const int*   dst    = (const int*)d_in[4];
    float* out = (float*)d_out;

    const int n_nodes = in_sizes[0] / IN_F;
    const int n_edges = in_sizes[3];
    const int nbuck   = (n_nodes + BNODES - 1) >> BSH;

    char* ws = (char*)d_ws;
    size_t off = 0;
    auto alloc = [&](size_t bytes) {
        char* p = ws + off;
        off += (bytes + 15) & ~(size_t)15;
        return p;
    };
    unsigned short* h  = (unsigned short*)alloc((size_t)(n_nodes + BM) * OUT_F * 2); // +BM pad rows
    float* norm        = (float*)alloc((size_t)n_nodes * 4);
    int*   rstart      = (int*)alloc(((size_t)n_nodes + 1) * 4);
    int*   bhist       = (int*)alloc(2 * MAXBUCK * 4);   // bhist | gcur0
    int*   gcur0       = bhist + MAXBUCK;
    int*   perbhist    = (int*)alloc((size_t)BIN1A_BLOCKS * MAXBUCK * 4);  // 1 MB
    unsigned short* Wt = (unsigned short*)alloc((size_t)OUT_F * IN_F * 2);
    unsigned* ebuf     = (unsigned*)alloc((size_t)n_edges * 4);
    int*   eidx        = (int*)alloc((size_t)n_edges * 4);

    hipMemsetAsync(bhist, 0, 2 * MAXBUCK * sizeof(int), stream);
    // K1: bin1a (+perbhist) || wprep
    prep_kernel<<<BIN1A_BLOCKS + OUT_F, 256, 0, stream>>>(weight, Wt, dst, bhist,
                                                          perbhist, n_edges, nbuck);
    // K2: gemm (3-deep counted-vmcnt pipeline, B in registers, 96 KB LDS)
    gemm_mfma<<<GEMM_BLOCKS, 1024, 0, stream>>>(feat, Wt, h, n_nodes);
    // K3: binning into bucket-grouped ebuf
    bin1b_kernel<<<BIN1B_BLOCKS, 1024, 0, stream>>>(src, dst, bhist, perbhist,
                                                    gcur0, ebuf, n_edges, nbuck);
    // K4: exact CSR
    bin2_kernel<<<nbuck, 256, 0, stream>>>(ebuf, bhist, rstart, norm, eidx,
                                           n_nodes, nbuck);
    // K5: aggregate
    agg_kernel<<<(n_nodes + 3) / 4, 256, 0, stream>>>(h, eidx, rstart, norm, bias, out, n_nodes);
}